// Round 10
// baseline (181.624 us; speedup 1.0000x reference)
//
#include <hip/hip_runtime.h>

typedef __bf16 bf16x8 __attribute__((ext_vector_type(8)));
typedef float f32x4 __attribute__((ext_vector_type(4)));
typedef unsigned short u16x8 __attribute__((ext_vector_type(8)));
typedef unsigned short u16x4 __attribute__((ext_vector_type(4)));

#define MFMA16(a, b, c) __builtin_amdgcn_mfma_f32_16x16x32_bf16((a), (b), (c), 0, 0, 0)

#define WAIT_VM3  asm volatile("s_waitcnt vmcnt(3)" ::: "memory")
#define WAIT_VM2  asm volatile("s_waitcnt vmcnt(2)" ::: "memory")
#define WAIT_VM0  asm volatile("s_waitcnt vmcnt(0)" ::: "memory")
#define WAIT_LGKM asm volatile("s_waitcnt lgkmcnt(0)" ::: "memory")
#define BAR       __builtin_amdgcn_s_barrier()

__device__ __forceinline__ unsigned short f2bf(float f) {
  union { float f; unsigned int i; } v; v.f = f;
  unsigned int u = v.i;
  u += 0x7fffu + ((u >> 16) & 1u);   // RNE
  return (unsigned short)(u >> 16);
}

// async global->LDS, 16B per lane. LDS dest = wave-uniform base + lane*16.
__device__ __forceinline__ void gload16(const void* g, void* l) {
  __builtin_amdgcn_global_load_lds(
      (const __attribute__((address_space(1))) unsigned int*)g,
      (__attribute__((address_space(3))) unsigned int*)l, 16, 0, 0);
}

// ---------------------------------------------------------------------------
// prep: ONE kernel = convert_x + transpose(W_qkv) + transpose(W_out).
// Round-10 buffer re-layout frees ws so W_out^T is produced up front:
//   blocks [0,2048):    x fp32 -> Xb bf16 (8 elems/thread)
//   blocks [2048,5120): W_qkv [1024][3072] -> Wqt [3072][1024] bf16
//   blocks [5120,6144): W_out [1024][1024] -> Wot [1024][1024] bf16
// Saves 2 launches and removes the transpose bubble between attn and gemm_bt64.
// ---------------------------------------------------------------------------
__global__ __launch_bounds__(256) void prep(
    const float* __restrict__ X, const float* __restrict__ Wq,
    const float* __restrict__ Wo, unsigned short* __restrict__ Xb,
    unsigned short* __restrict__ Wqt, unsigned short* __restrict__ Wot) {
  __shared__ unsigned short t[32][33];
  int id = blockIdx.x;
  if (id < 2048) {
    size_t i = (size_t)(id * 256 + threadIdx.x) * 8;
    f32x4 f0 = *(const f32x4*)(X + i);
    f32x4 f1 = *(const f32x4*)(X + i + 4);
    u16x8 tt;
#pragma unroll
    for (int j = 0; j < 4; ++j) { tt[j] = f2bf(f0[j]); tt[4 + j] = f2bf(f1[j]); }
    *(u16x8*)(Xb + i) = tt;
    return;
  }
  const float* W; unsigned short* Wt; int N, bx, by;
  if (id < 5120) { int q = id - 2048; W = Wq; Wt = Wqt; N = 3072; bx = q % 96; by = q / 96; }
  else           { int q = id - 5120; W = Wo; Wt = Wot; N = 1024; bx = q % 32; by = q / 32; }
  int tx = threadIdx.x & 31, ty = threadIdx.x >> 5;   // 32 x 8
#pragma unroll
  for (int j = 0; j < 4; ++j) {
    int r = ty + j * 8;
    t[tx][r] = f2bf(W[(size_t)(by * 32 + r) * N + bx * 32 + tx]);
  }
  __syncthreads();
#pragma unroll
  for (int j = 0; j < 4; ++j) {
    int r = ty + j * 8;   // output row (N index)
    Wt[(size_t)(bx * 32 + r) * 1024 + by * 32 + tx] = t[r][tx];
  }
}

// ---------------------------------------------------------------------------
// gemm_bt, round 10: 128x64 tile, 256 thr / 4 waves (2M x 2N), BK=32,
// counted-vmcnt double buffer. Occupancy play: LDS 24KB dbuf + VGPR ~92 ->
// ~5 blocks/CU (vs 3 for the 512-thr 128x128 version): the 2-phase loop's
// exposed stage latency is hidden by cross-block TLP only (R7 mechanism).
// Per-output accumulation order unchanged (same BK=32, same quad k-slice)
// -> bit-identical output. Staging: 2 A-chunks + 1 B-chunk per thread
// (3 vmcnt units per STAGE -> vmcnt(3) waits exactly the prior tile).
// mode 0: N=3072, scatter Q[b,h,s,d], K[b,h,s,d], V[b,h,d,s] bf16.
// C-layout: col = lane&15, row = quad*4 + r (ref-verified lineage).
// ---------------------------------------------------------------------------
__global__ __launch_bounds__(256) void gemm_bt(
    const unsigned short* __restrict__ A, const unsigned short* __restrict__ Bt,
    const float* __restrict__ bias,
    unsigned short* __restrict__ O0, unsigned short* __restrict__ O1,
    unsigned short* __restrict__ O2, float* __restrict__ OF, int mode) {
  __shared__ __align__(16) unsigned short As0[128 * 32];
  __shared__ __align__(16) unsigned short Bs0[64 * 32];
  __shared__ __align__(16) unsigned short As1[128 * 32];
  __shared__ __align__(16) unsigned short Bs1[64 * 32];

  const int K = 1024;
  int tid = threadIdx.x;
  int lane = tid & 63, wave = tid >> 6, quad = lane >> 4, l16 = lane & 15;
  int wr = wave >> 1, wc = wave & 1;
  int m0 = blockIdx.x * 128, n0 = blockIdx.y * 64;

  // staging: A 512 chunks (2/thread), B 256 chunks (1/thread); chunk c:
  // row = c>>2, 16B-unit = c&3; LDS byte offset = c*16 (row-major [*][32]).
  int srow = tid >> 2, su = tid & 3;
  const unsigned short* ag0 = A + (size_t)(m0 + srow) * K + su * 8;
  const unsigned short* ag1 = A + (size_t)(m0 + 64 + srow) * K + su * 8;
  const unsigned short* bg  = Bt + (size_t)(n0 + srow) * K + su * 8;
  int aoff0 = tid * 16, aoff1 = (tid + 256) * 16, boff = tid * 16;

  int abase = (wr * 64 + l16) * 64 + quad * 16;   // + mt*1024, mt 0..3
  int bbase = (wc * 32 + l16) * 64 + quad * 16;   // + nt*1024, nt 0..1

  f32x4 acc[4][2];
#pragma unroll
  for (int i = 0; i < 4; ++i)
#pragma unroll
    for (int j = 0; j < 2; ++j) acc[i][j] = f32x4{0.f, 0.f, 0.f, 0.f};

  auto STAGE = [&](int k0, char* Asb, char* Bsb) {
    gload16(ag0 + k0, Asb + aoff0);
    gload16(ag1 + k0, Asb + aoff1);
    gload16(bg + k0, Bsb + boff);
  };
  auto COMPUTE = [&](const char* Asb, const char* Bsb) {
    bf16x8 af[4], bfr[2];
#pragma unroll
    for (int t = 0; t < 4; ++t)
      af[t] = *(const bf16x8*)(Asb + abase + t * 1024);
#pragma unroll
    for (int t = 0; t < 2; ++t)
      bfr[t] = *(const bf16x8*)(Bsb + bbase + t * 1024);
#pragma unroll
    for (int mt = 0; mt < 4; ++mt)
#pragma unroll
      for (int nt = 0; nt < 2; ++nt)
        acc[mt][nt] = MFMA16(af[mt], bfr[nt], acc[mt][nt]);
  };

  STAGE(0, (char*)As0, (char*)Bs0);               // prologue: tile 0 in flight
  for (int t = 0; t < 30; t += 2) {
    STAGE((t + 1) * 32, (char*)As1, (char*)Bs1);  // tile t+1 -> buf1
    WAIT_VM3; BAR;                                // tile t landed
    COMPUTE((const char*)As0, (const char*)Bs0);
    WAIT_LGKM; BAR;                               // buf0 free for reuse
    STAGE((t + 2) * 32, (char*)As0, (char*)Bs0);  // tile t+2 -> buf0
    WAIT_VM3; BAR;                                // tile t+1 landed
    COMPUTE((const char*)As1, (const char*)Bs1);
    WAIT_LGKM; BAR;                               // buf1 free for reuse
  }
  STAGE(31 * 32, (char*)As1, (char*)Bs1);         // last tile -> buf1
  WAIT_VM3; BAR;
  COMPUTE((const char*)As0, (const char*)Bs0);
  WAIT_LGKM; BAR;
  WAIT_VM0; BAR;                                  // drain last tile
  COMPUTE((const char*)As1, (const char*)Bs1);

  if (mode == 0) {
#pragma unroll
    for (int nt = 0; nt < 2; ++nt) {
      int n = n0 + wc * 32 + nt * 16 + l16;
      float bv = bias[n];
      int seg = n >> 10, cc = n & 1023, hh = cc >> 6, d = cc & 63;
#pragma unroll
      for (int mt = 0; mt < 4; ++mt) {
        int mb = m0 + wr * 64 + mt * 16 + quad * 4;
        int b = mb >> 11, s = mb & 2047;
        if (seg == 2) {
          u16x4 pk;
#pragma unroll
          for (int r = 0; r < 4; ++r) pk[r] = f2bf(acc[mt][nt][r] + bv);
          *(u16x4*)&O2[((size_t)((b << 4) + hh) * 64 + d) * 2048 + s] = pk;  // V[b,h,d,s]
        } else {
          unsigned short* O = seg ? O1 : O0;
#pragma unroll
          for (int r = 0; r < 4; ++r)
            O[((size_t)((b << 4) + hh) * 2048 + (s + r)) * 64 + d] = f2bf(acc[mt][nt][r] + bv);
        }
      }
    }
  } else {
#pragma unroll
    for (int nt = 0; nt < 2; ++nt) {
      int n = n0 + wc * 32 + nt * 16 + l16;
      float bv = bias[n];
#pragma unroll
      for (int mt = 0; mt < 4; ++mt) {
        int mb = m0 + wr * 64 + mt * 16 + quad * 4;
#pragma unroll
        for (int r = 0; r < 4; ++r)
          OF[(size_t)(mb + r) * 1024 + n] = acc[mt][nt][r] + bv;   // FP32 output
      }
    }
  }
}

// ---------------------------------------------------------------------------
// gemm_bt64: output-projection GEMM (frozen from round 7).
// OF[4096 x 1024] = A @ Bt^T + b. Tile 64x64, 256 thr / 4 waves, acc[2][2];
// grid (64,16)=1024 blocks = 4 blocks/CU of independent streams.
// ---------------------------------------------------------------------------
__global__ __launch_bounds__(256) void gemm_bt64(
    const unsigned short* __restrict__ A, const unsigned short* __restrict__ Bt,
    const float* __restrict__ bias, float* __restrict__ OF) {
  __shared__ __align__(16) unsigned short As0[64 * 32];
  __shared__ __align__(16) unsigned short Bs0[64 * 32];
  __shared__ __align__(16) unsigned short As1[64 * 32];
  __shared__ __align__(16) unsigned short Bs1[64 * 32];

  const int K = 1024;
  int tid = threadIdx.x;
  int lane = tid & 63, wave = tid >> 6, quad = lane >> 4, l16 = lane & 15;
  int wr = wave >> 1, wc = wave & 1;
  int m0 = blockIdx.x * 64, n0 = blockIdx.y * 64;

  int srow = tid >> 2, su = tid & 3;
  const unsigned short* ag = A + (size_t)(m0 + srow) * K + su * 8;
  const unsigned short* bg = Bt + (size_t)(n0 + srow) * K + su * 8;
  int loff = tid * 16;

  int abase = (wr * 32 + l16) * 64 + quad * 16;   // + mt*1024, mt 0..1
  int bbase = (wc * 32 + l16) * 64 + quad * 16;   // + nt*1024, nt 0..1

  f32x4 acc[2][2];
#pragma unroll
  for (int i = 0; i < 2; ++i)
#pragma unroll
    for (int j = 0; j < 2; ++j) acc[i][j] = f32x4{0.f, 0.f, 0.f, 0.f};

  auto STAGE = [&](int k0, char* Asb, char* Bsb) {
    gload16(ag + k0, Asb + loff);
    gload16(bg + k0, Bsb + loff);
  };
  auto COMPUTE = [&](const char* Asb, const char* Bsb) {
    bf16x8 af[2], bfr[2];
#pragma unroll
    for (int t = 0; t < 2; ++t) {
      af[t]  = *(const bf16x8*)(Asb + abase + t * 1024);
      bfr[t] = *(const bf16x8*)(Bsb + bbase + t * 1024);
    }
#pragma unroll
    for (int mt = 0; mt < 2; ++mt)
#pragma unroll
      for (int nt = 0; nt < 2; ++nt)
        acc[mt][nt] = MFMA16(af[mt], bfr[nt], acc[mt][nt]);
  };

  STAGE(0, (char*)As0, (char*)Bs0);               // prologue: tile 0 in flight
  for (int t = 0; t < 30; t += 2) {
    STAGE((t + 1) * 32, (char*)As1, (char*)Bs1);  // tile t+1 -> buf1
    WAIT_VM2; BAR;                                // tile t landed
    COMPUTE((const char*)As0, (const char*)Bs0);
    WAIT_LGKM; BAR;                               // buf0 free for reuse
    STAGE((t + 2) * 32, (char*)As0, (char*)Bs0);  // tile t+2 -> buf0
    WAIT_VM2; BAR;                                // tile t+1 landed
    COMPUTE((const char*)As1, (const char*)Bs1);
    WAIT_LGKM; BAR;                               // buf1 free for reuse
  }
  STAGE(31 * 32, (char*)As1, (char*)Bs1);         // last tile -> buf1
  WAIT_VM2; BAR;
  COMPUTE((const char*)As0, (const char*)Bs0);
  WAIT_LGKM; BAR;
  WAIT_VM0; BAR;                                  // drain last tile
  COMPUTE((const char*)As1, (const char*)Bs1);

#pragma unroll
  for (int nt = 0; nt < 2; ++nt) {
    int n = n0 + wc * 32 + nt * 16 + l16;
    float bv = bias[n];
#pragma unroll
    for (int mt = 0; mt < 2; ++mt) {
      int mb = m0 + wr * 32 + mt * 16 + quad * 4;
#pragma unroll
      for (int r = 0; r < 4; ++r)
        OF[(size_t)(mb + r) * 1024 + n] = acc[mt][nt][r] + bv;   // FP32 output
    }
  }
}

// ---------------------------------------------------------------------------
// MFMA windowed flash attention (round-9 passing version + EXACT defer-
// rescale). When __any(vmax > m) is false: mnew == m, alpha == exp(0) == 1,
// so the rescale (o*=1, l*=1) is the identity — skip it, bit-exact. The
// branch is wave-uniform (__any). Saves ~30 VALU + 4 shfl on non-growing
// phases (roughly half of the 9). All other logic identical to round 9.
// ---------------------------------------------------------------------------
__global__ __launch_bounds__(256) void attn_kernel(
    const unsigned short* __restrict__ Q, const unsigned short* __restrict__ Kq,
    const unsigned short* __restrict__ Vt, unsigned short* __restrict__ AO) {
  __shared__ __align__(16) unsigned short Ps[4][16][40];   // per-wave P: [q][key]

  int bid = blockIdx.x;
  int qblk = bid & 31, h = (bid >> 5) & 15, b = bid >> 9;
  int q0 = qblk * 64;
  int tid = threadIdx.x, lane = tid & 63, wave = tid >> 6, quad = lane >> 4, l16 = lane & 15;

  const unsigned short* Qb = Q + (size_t)(((b << 4) + h) * 2048) * 64;
  const unsigned short* Kb = Kq + (size_t)(((b << 4) + h) * 2048) * 64;
  const unsigned short* Vb = Vt + (size_t)(((b << 4) + h) * 64) * 2048;

  int qg = q0 + wave * 16 + l16;   // this lane's query row (A/B frag row)
  bf16x8 qf0 = __builtin_bit_cast(bf16x8, *(const u16x8*)&Qb[(size_t)qg * 64 + quad * 8]);
  bf16x8 qf1 = __builtin_bit_cast(bf16x8, *(const u16x8*)&Qb[(size_t)qg * 64 + 32 + quad * 8]);

  float m = -1e30f, l = 0.f;
  f32x4 zero = {0.f, 0.f, 0.f, 0.f};
  f32x4 o[4];
#pragma unroll
  for (int i = 0; i < 4; ++i) o[i] = zero;

  const float SCALE = 0.125f;  // 64^-0.5
  int pstart = (wave >= 2) ? 1 : 0;
  int pend = pstart + 8;

  for (int p = pstart; p <= pend; ++p) {
    int kbase = q0 + p * 32;

    // ---- S^T = K Q^T : swapped operands ----
    f32x4 sc[2];
    __builtin_amdgcn_s_setprio(1);
#pragma unroll
    for (int t = 0; t < 2; ++t) {
      int krow = kbase + t * 16 + l16;
      krow = krow > 2047 ? 2047 : krow;
      bf16x8 kf0 = __builtin_bit_cast(bf16x8, *(const u16x8*)&Kb[(size_t)krow * 64 + quad * 8]);
      bf16x8 kf1 = __builtin_bit_cast(bf16x8, *(const u16x8*)&Kb[(size_t)krow * 64 + 32 + quad * 8]);
      f32x4 z = zero;
      z = MFMA16(kf0, qf0, z);
      z = MFMA16(kf1, qf1, z);
      sc[t] = z;   // sc[t][r] = S[q=l16][key = kbase + t*16 + quad*4 + r]
    }
    __builtin_amdgcn_s_setprio(0);

    // ---- V frags: issue now; softmax hides the latency ----
    bf16x8 vf[4];
    {
      int vcol = kbase + quad * 8;
      vcol = vcol > 2040 ? 2040 : vcol;   // 16B group fully valid or fully P=0
#pragma unroll
      for (int nt = 0; nt < 4; ++nt)
        vf[nt] = __builtin_bit_cast(bf16x8,
            *(const u16x8*)&Vb[(size_t)(nt * 16 + l16) * 2048 + vcol]);
    }

    // ---- mask (query fixed per lane; r indexes KEY) ----
    float sv[2][4];
#pragma unroll
    for (int t = 0; t < 2; ++t)
#pragma unroll
      for (int r = 0; r < 4; ++r) {
        int kg = kbase + t * 16 + quad * 4 + r;
        bool valid = (kg >= qg) && (kg <= qg + 255) && (kg < 2048);
        sv[t][r] = valid ? sc[t][r] * SCALE : -1e30f;
      }

    // ---- lane-local online softmax ----
    float vmax = fmaxf(fmaxf(fmaxf(sv[0][0], sv[0][1]), fmaxf(sv[0][2], sv[0][3])),
                       fmaxf(fmaxf(sv[1][0], sv[1][1]), fmaxf(sv[1][2], sv[1][3])));
    vmax = fmaxf(vmax, __shfl_xor(vmax, 16));
    vmax = fmaxf(vmax, __shfl_xor(vmax, 32));
    float mnew = fmaxf(m, vmax);
    float pe[2][4];
#pragma unroll
    for (int t = 0; t < 2; ++t)
#pragma unroll
      for (int r = 0; r < 4; ++r) {
        float e = __expf(sv[t][r] - mnew);
        pe[t][r] = (sv[t][r] > -5e29f) ? e : 0.f;
      }
    float rs = ((pe[0][0] + pe[0][1]) + (pe[0][2] + pe[0][3])) +
               ((pe[1][0] + pe[1][1]) + (pe[1][2] + pe[1][3]));
    rs += __shfl_xor(rs, 16);
    rs += __shfl_xor(rs, 32);

    if (__any(vmax > m)) {
      // some query's max grew: full rescale path (alpha==1 exactly for
      // queries that did not grow — handled per-lane by the shuffle).
      float alpha = __expf(m - mnew);   // alpha for query l16 (quad-uniform)
      m = mnew;
      l = l * alpha + rs;
      f32x4 av;
#pragma unroll
      for (int r = 0; r < 4; ++r) av[r] = __shfl(alpha, quad * 4 + r);
#pragma unroll
      for (int nt = 0; nt < 4; ++nt) o[nt] *= av;
    } else {
      l += rs;                          // mnew==m, alpha==1: identity rescale
    }

    // ---- P -> LDS (2 packed 8B writes), read back as A-frag ----
#pragma unroll
    for (int t = 0; t < 2; ++t) {
      u16x4 pk;
#pragma unroll
      for (int r = 0; r < 4; ++r) pk[r] = f2bf(pe[t][r]);
      *(u16x4*)&Ps[wave][l16][t * 16 + quad * 4] = pk;
    }
    __threadfence_block();
    bf16x8 pf = __builtin_bit_cast(bf16x8, *(const u16x8*)&Ps[wave][l16][quad * 8]);

    // ---- O += P V (4 MFMA); o rows = queries quad*4+r ----
    __builtin_amdgcn_s_setprio(1);
#pragma unroll
    for (int nt = 0; nt < 4; ++nt)
      o[nt] = MFMA16(pf, vf[nt], o[nt]);
    __builtin_amdgcn_s_setprio(0);
  }

  // ---- broadcast per-query l across quads via LDS scratch ----
  __threadfence_block();
  float* Lf = (float*)&Ps[wave][0][0];
  Lf[l16] = l;                         // 4 quads write same value to same addr
  __threadfence_block();
  float lr[4];
#pragma unroll
  for (int r = 0; r < 4; ++r) lr[r] = Lf[quad * 4 + r];

  unsigned short* dst = AO + ((size_t)(b * 2048 + q0 + wave * 16) * 1024) + h * 64;
#pragma unroll
  for (int nt = 0; nt < 4; ++nt)
#pragma unroll
    for (int r = 0; r < 4; ++r) {
      int qq = quad * 4 + r;
      dst[(size_t)qq * 1024 + nt * 16 + l16] = f2bf(o[nt][r] / lr[r]);
    }
}

extern "C" void kernel_launch(void* const* d_in, const int* in_sizes, int n_in,
                              void* d_out, int out_size, void* d_ws, size_t ws_size,
                              hipStream_t stream) {
  const float* x = (const float*)d_in[0];
  const float* W_qkv = (const float*)d_in[1];
  const float* b_qkv = (const float*)d_in[2];
  const float* W_out = (const float*)d_in[3];
  const float* b_out = (const float*)d_in[4];
  float* out = (float*)d_out;

  // Round-10 layout (ws 32 MiB = 16M shorts; d_out 16 MiB = 8M shorts):
  //   ws:    Qw  [0, 4M)       Kw  [4M, 8M)
  //          Wqt [8M, 11M)     Wot [11M, 12M)   AO [12M, 16M)   (shorts)
  //   d_out: Xb  [0, 4M)       Vw  [4M, 8M)     (shorts; both dead before
  //          gemm_bt64 overwrites d_out with the fp32 result)
  // Lifetimes: prep writes Xb,Wqt,Wot. gemm0 reads Xb,Wqt; writes Qw,Kw,Vw.
  // attn reads Qw,Kw,Vw; writes AO (never touches Wot). gemm_bt64 reads
  // AO,Wot; writes d_out. No region is read after something overwrote it.
  unsigned short* ws = (unsigned short*)d_ws;
  unsigned short* Qw  = ws;                      // [b,h,s,d] bf16
  unsigned short* Kw  = ws + 4194304;            // [b,h,s,d] bf16
  unsigned short* Wqt = ws + 8388608;            // [3072][1024] bf16 = W_qkv^T
  unsigned short* Wot = ws + 11534336;           // [1024][1024] bf16 = W_out^T
  unsigned short* AO  = ws + 12582912;           // [b,s,h*64+d] bf16
  unsigned short* Xb  = (unsigned short*)d_out;  // [4096][1024] bf16
  unsigned short* Vw  = (unsigned short*)d_out + 4194304;  // [b,h,d,s] bf16

  dim3 blk(256);
  prep<<<dim3(6144), blk, 0, stream>>>(x, W_qkv, W_out, Xb, Wqt, Wot);
  gemm_bt<<<dim3(32, 48), blk, 0, stream>>>(Xb, Wqt, b_qkv, Qw, Kw, Vw, nullptr, 0);
  attn_kernel<<<dim3(1024), blk, 0, stream>>>(Qw, Kw, Vw, AO);
  gemm_bt64<<<dim3(64, 16), blk, 0, stream>>>(AO, Wot, b_out, out);
}

// Round 11
// 165.610 us; speedup vs baseline: 1.0967x; 1.0967x over previous
//
#include <hip/hip_runtime.h>

typedef __bf16 bf16x8 __attribute__((ext_vector_type(8)));
typedef float f32x4 __attribute__((ext_vector_type(4)));
typedef unsigned short u16x8 __attribute__((ext_vector_type(8)));
typedef unsigned short u16x4 __attribute__((ext_vector_type(4)));

#define MFMA16(a, b, c) __builtin_amdgcn_mfma_f32_16x16x32_bf16((a), (b), (c), 0, 0, 0)

#define WAIT_VM2  asm volatile("s_waitcnt vmcnt(2)" ::: "memory")
#define WAIT_VM0  asm volatile("s_waitcnt vmcnt(0)" ::: "memory")
#define WAIT_LGKM asm volatile("s_waitcnt lgkmcnt(0)" ::: "memory")
#define BAR       __builtin_amdgcn_s_barrier()

__device__ __forceinline__ unsigned short f2bf(float f) {
  union { float f; unsigned int i; } v; v.f = f;
  unsigned int u = v.i;
  u += 0x7fffu + ((u >> 16) & 1u);   // RNE
  return (unsigned short)(u >> 16);
}

// async global->LDS, 16B per lane. LDS dest = wave-uniform base + lane*16.
__device__ __forceinline__ void gload16(const void* g, void* l) {
  __builtin_amdgcn_global_load_lds(
      (const __attribute__((address_space(1))) unsigned int*)g,
      (__attribute__((address_space(3))) unsigned int*)l, 16, 0, 0);
}

// ---------------------------------------------------------------------------
// prep: ONE kernel = convert_x + transpose(W_qkv) + transpose(W_out).
// (The only change vs the round-3 champion config: 3 launches -> 1.)
//   blocks [0,2048):    x fp32 -> Xb bf16 (8 elems/thread)
//   blocks [2048,5120): W_qkv [1024][3072] -> Wqt [3072][1024] bf16
//   blocks [5120,6144): W_out [1024][1024] -> Wot [1024][1024] bf16
// ---------------------------------------------------------------------------
__global__ __launch_bounds__(256) void prep(
    const float* __restrict__ X, const float* __restrict__ Wq,
    const float* __restrict__ Wo, unsigned short* __restrict__ Xb,
    unsigned short* __restrict__ Wqt, unsigned short* __restrict__ Wot) {
  __shared__ unsigned short t[32][33];
  int id = blockIdx.x;
  if (id < 2048) {
    size_t i = (size_t)(id * 256 + threadIdx.x) * 8;
    f32x4 f0 = *(const f32x4*)(X + i);
    f32x4 f1 = *(const f32x4*)(X + i + 4);
    u16x8 tt;
#pragma unroll
    for (int j = 0; j < 4; ++j) { tt[j] = f2bf(f0[j]); tt[4 + j] = f2bf(f1[j]); }
    *(u16x8*)(Xb + i) = tt;
    return;
  }
  const float* W; unsigned short* Wt; int N, bx, by;
  if (id < 5120) { int q = id - 2048; W = Wq; Wt = Wqt; N = 3072; bx = q % 96; by = q / 96; }
  else           { int q = id - 5120; W = Wo; Wt = Wot; N = 1024; bx = q % 32; by = q / 32; }
  int tx = threadIdx.x & 31, ty = threadIdx.x >> 5;   // 32 x 8
#pragma unroll
  for (int j = 0; j < 4; ++j) {
    int r = ty + j * 8;
    t[tx][r] = f2bf(W[(size_t)(by * 32 + r) * N + bx * 32 + tx]);
  }
  __syncthreads();
#pragma unroll
  for (int j = 0; j < 4; ++j) {
    int r = ty + j * 8;   // output row (N index)
    Wt[(size_t)(bx * 32 + r) * 1024 + by * 32 + tx] = t[r][tx];
  }
}

// ---------------------------------------------------------------------------
// m97-lineage GEMM, 8-wave variant + T4 counted-vmcnt double buffer.
// (EXACT round-3 champion version — the best-measured GEMM config: 170.2us
// total. 128x64 variant of R10 measured WORSE: 52.5us, conflicts 4.7M.)
// C[M x N] = A[M x 1024] @ Bt[N x 1024]^T + bias, fp32 acc.
// Tile 128x128, BK=32, 512 thr = 8 waves (2M x 4N); wave owns 64x32.
// mode 0: N=3072, scatter Q[b,h,s,d], K[b,h,s,d], V[b,h,d,s] bf16.
// mode 1: N=1024, store FP32 to OF[m*1024+n].
// ---------------------------------------------------------------------------
__global__ __launch_bounds__(512) void gemm_bt(
    const unsigned short* __restrict__ A, const unsigned short* __restrict__ Bt,
    const float* __restrict__ bias,
    unsigned short* __restrict__ O0, unsigned short* __restrict__ O1,
    unsigned short* __restrict__ O2, float* __restrict__ OF, int mode) {
  __shared__ __align__(16) unsigned short As0[128 * 32];
  __shared__ __align__(16) unsigned short Bs0[128 * 32];
  __shared__ __align__(16) unsigned short As1[128 * 32];
  __shared__ __align__(16) unsigned short Bs1[128 * 32];

  const int K = 1024;
  int tid = threadIdx.x;
  int lane = tid & 63, wave = tid >> 6, quad = lane >> 4, l16 = lane & 15;
  int wr = wave >> 2, wc = wave & 3;
  int m0 = blockIdx.x * 128, n0 = blockIdx.y * 128;

  int srow = tid >> 2, su = tid & 3;
  const unsigned short* ag = A + (size_t)(m0 + srow) * K + su * 8;
  const unsigned short* bg = Bt + (size_t)(n0 + srow) * K + su * 8;
  int loff = tid * 16;

  int abase = (wr * 64 + l16) * 64 + quad * 16;   // + mt*1024, mt 0..3
  int bbase = (wc * 32 + l16) * 64 + quad * 16;   // + nt*1024, nt 0..1

  f32x4 acc[4][2];
#pragma unroll
  for (int i = 0; i < 4; ++i)
#pragma unroll
    for (int j = 0; j < 2; ++j) acc[i][j] = f32x4{0.f, 0.f, 0.f, 0.f};

  auto STAGE = [&](int k0, char* Asb, char* Bsb) {
    gload16(ag + k0, Asb + loff);
    gload16(bg + k0, Bsb + loff);
  };
  auto COMPUTE = [&](const char* Asb, const char* Bsb) {
    bf16x8 af[4], bfr[2];
#pragma unroll
    for (int t = 0; t < 4; ++t)
      af[t] = *(const bf16x8*)(Asb + abase + t * 1024);
#pragma unroll
    for (int t = 0; t < 2; ++t)
      bfr[t] = *(const bf16x8*)(Bsb + bbase + t * 1024);
#pragma unroll
    for (int mt = 0; mt < 4; ++mt)
#pragma unroll
      for (int nt = 0; nt < 2; ++nt)
        acc[mt][nt] = MFMA16(af[mt], bfr[nt], acc[mt][nt]);
  };

  STAGE(0, (char*)As0, (char*)Bs0);               // prologue: tile 0 in flight
  for (int t = 0; t < 30; t += 2) {
    STAGE((t + 1) * 32, (char*)As1, (char*)Bs1);  // tile t+1 -> buf1
    WAIT_VM2; BAR;                                // tile t landed
    COMPUTE((const char*)As0, (const char*)Bs0);
    WAIT_LGKM; BAR;                               // buf0 free for reuse
    STAGE((t + 2) * 32, (char*)As0, (char*)Bs0);  // tile t+2 -> buf0
    WAIT_VM2; BAR;                                // tile t+1 landed
    COMPUTE((const char*)As1, (const char*)Bs1);
    WAIT_LGKM; BAR;                               // buf1 free for reuse
  }
  STAGE(31 * 32, (char*)As1, (char*)Bs1);         // last tile -> buf1
  WAIT_VM2; BAR;
  COMPUTE((const char*)As0, (const char*)Bs0);
  WAIT_LGKM; BAR;
  WAIT_VM0; BAR;                                  // drain last tile
  COMPUTE((const char*)As1, (const char*)Bs1);

  if (mode == 0) {
#pragma unroll
    for (int nt = 0; nt < 2; ++nt) {
      int n = n0 + wc * 32 + nt * 16 + l16;
      float bv = bias[n];
      int seg = n >> 10, cc = n & 1023, hh = cc >> 6, d = cc & 63;
#pragma unroll
      for (int mt = 0; mt < 4; ++mt) {
        int mb = m0 + wr * 64 + mt * 16 + quad * 4;
        int b = mb >> 11, s = mb & 2047;
        if (seg == 2) {
          u16x4 pk;
#pragma unroll
          for (int r = 0; r < 4; ++r) pk[r] = f2bf(acc[mt][nt][r] + bv);
          *(u16x4*)&O2[((size_t)((b << 4) + hh) * 64 + d) * 2048 + s] = pk;  // V[b,h,d,s]
        } else {
          unsigned short* O = seg ? O1 : O0;
#pragma unroll
          for (int r = 0; r < 4; ++r)
            O[((size_t)((b << 4) + hh) * 2048 + (s + r)) * 64 + d] = f2bf(acc[mt][nt][r] + bv);
        }
      }
    }
  } else {
#pragma unroll
    for (int nt = 0; nt < 2; ++nt) {
      int n = n0 + wc * 32 + nt * 16 + l16;
      float bv = bias[n];
#pragma unroll
      for (int mt = 0; mt < 4; ++mt) {
        int mb = m0 + wr * 64 + mt * 16 + quad * 4;
#pragma unroll
        for (int r = 0; r < 4; ++r)
          OF[(size_t)(mb + r) * 1024 + n] = acc[mt][nt][r] + bv;   // FP32 output
      }
    }
  }
}

// ---------------------------------------------------------------------------
// MFMA windowed flash attention — EXACT round-3 champion version (LDS-staged
// K/V, 4 waves, per-row online softmax). Cross-round ledger: every variant
// (de-staged R5 +3.9us, KVBLK=64 R6 +4, swapped-softmax R9 ~0, defer R10)
// measured neutral-or-worse IN CONTEXT vs this one. Restored byte-for-byte.
// ---------------------------------------------------------------------------
__global__ __launch_bounds__(256) void attn_kernel(
    const unsigned short* __restrict__ Q, const unsigned short* __restrict__ Kq,
    const unsigned short* __restrict__ Vt, unsigned short* __restrict__ AO) {
  __shared__ __align__(16) unsigned short Ks[32][72];      // [key][d]
  __shared__ __align__(16) unsigned short Vs[64][40];      // [d][key]
  __shared__ __align__(16) unsigned short Ps[4][16][40];   // per-wave P: [q][key]

  int bid = blockIdx.x;
  int qblk = bid & 31, h = (bid >> 5) & 15, b = bid >> 9;
  int q0 = qblk * 64;
  int tid = threadIdx.x, lane = tid & 63, wave = tid >> 6, quad = lane >> 4, l16 = lane & 15;

  const unsigned short* Qb = Q + (size_t)(((b << 4) + h) * 2048) * 64;
  const unsigned short* Kb = Kq + (size_t)(((b << 4) + h) * 2048) * 64;
  const unsigned short* Vb = Vt + (size_t)(((b << 4) + h) * 64) * 2048;

  int qrow = q0 + wave * 16 + l16;   // A-frag row m = lane&15
  bf16x8 qf0 = __builtin_bit_cast(bf16x8, *(const u16x8*)&Qb[(size_t)qrow * 64 + quad * 8]);
  bf16x8 qf1 = __builtin_bit_cast(bf16x8, *(const u16x8*)&Qb[(size_t)qrow * 64 + 32 + quad * 8]);

  float mrow[4], lrow[4];
  f32x4 zero = {0.f, 0.f, 0.f, 0.f};
  f32x4 o[4];
#pragma unroll
  for (int i = 0; i < 4; ++i) o[i] = zero;
#pragma unroll
  for (int r = 0; r < 4; ++r) { mrow[r] = -1e30f; lrow[r] = 0.f; }

  const float SCALE = 0.125f;  // 64^-0.5
  int pstart = (wave >= 2) ? 1 : 0;
  int pend = pstart + 8;

  int ki = tid >> 3, kc = (tid & 7) * 8;   // K stage: 32 keys x 64 d
  int vd = tid >> 2, vc = (tid & 3) * 8;   // V stage: 64 d x 32 keys

  for (int p = 0; p < 10; ++p) {
    int kbase = q0 + p * 32;
    {
      int s = kbase + ki; s = s > 2047 ? 2047 : s;   // clamp; masked later
      *(u16x8*)&Ks[ki][kc] = *(const u16x8*)&Kb[(size_t)s * 64 + kc];
    }
    if (kbase + vc + 7 <= 2047) {
      *(u16x8*)&Vs[vd][vc] = *(const u16x8*)&Vb[(size_t)vd * 2048 + kbase + vc];
    } else {
#pragma unroll
      for (int j = 0; j < 8; ++j) {
        int s = kbase + vc + j; s = s > 2047 ? 2047 : s;
        Vs[vd][vc + j] = Vb[(size_t)vd * 2048 + s];
      }
    }
    __syncthreads();

    if (p >= pstart && p <= pend) {
      // S = Q K^T : B-frag = K[key=lane&15][d=quad*8+j]
      f32x4 sc[2];
#pragma unroll
      for (int t = 0; t < 2; ++t) {
        bf16x8 kf0 = __builtin_bit_cast(bf16x8, *(const u16x8*)&Ks[t * 16 + l16][quad * 8]);
        bf16x8 kf1 = __builtin_bit_cast(bf16x8, *(const u16x8*)&Ks[t * 16 + l16][32 + quad * 8]);
        f32x4 z = zero;
        z = MFMA16(qf0, kf0, z);
        z = MFMA16(qf1, kf1, z);
        sc[t] = z;
      }
      float sv[2][4];
#pragma unroll
      for (int t = 0; t < 2; ++t)
#pragma unroll
        for (int r = 0; r < 4; ++r) {
          int kg = kbase + t * 16 + l16;
          int qg = q0 + wave * 16 + quad * 4 + r;
          bool valid = (kg >= qg) && (kg <= qg + 255) && (kg < 2048);
          sv[t][r] = valid ? sc[t][r] * SCALE : -1e30f;
        }
#pragma unroll
      for (int r = 0; r < 4; ++r) {
        float v = fmaxf(sv[0][r], sv[1][r]);
        v = fmaxf(v, __shfl_xor(v, 1));
        v = fmaxf(v, __shfl_xor(v, 2));
        v = fmaxf(v, __shfl_xor(v, 4));
        v = fmaxf(v, __shfl_xor(v, 8));
        float mnew = fmaxf(mrow[r], v);
        float alpha = __expf(mrow[r] - mnew);
        mrow[r] = mnew;
        float p0 = __expf(sv[0][r] - mnew);
        float p1 = __expf(sv[1][r] - mnew);
        p0 = (sv[0][r] > -5e29f) ? p0 : 0.f;
        p1 = (sv[1][r] > -5e29f) ? p1 : 0.f;
        float rs = p0 + p1;
        rs += __shfl_xor(rs, 1);
        rs += __shfl_xor(rs, 2);
        rs += __shfl_xor(rs, 4);
        rs += __shfl_xor(rs, 8);
        lrow[r] = lrow[r] * alpha + rs;
#pragma unroll
        for (int nt = 0; nt < 4; ++nt) o[nt][r] *= alpha;
        Ps[wave][quad * 4 + r][l16] = f2bf(p0);
        Ps[wave][quad * 4 + r][16 + l16] = f2bf(p1);
      }
      __threadfence_block();
      bf16x8 pf = __builtin_bit_cast(bf16x8, *(const u16x8*)&Ps[wave][l16][quad * 8]);
#pragma unroll
      for (int nt = 0; nt < 4; ++nt) {
        bf16x8 vf = __builtin_bit_cast(bf16x8, *(const u16x8*)&Vs[nt * 16 + l16][quad * 8]);
        o[nt] = MFMA16(pf, vf, o[nt]);
      }
    }
    __syncthreads();
  }

  unsigned short* dst = AO + ((size_t)(b * 2048 + q0 + wave * 16) * 1024) + h * 64;
#pragma unroll
  for (int nt = 0; nt < 4; ++nt)
#pragma unroll
    for (int r = 0; r < 4; ++r) {
      int qq = quad * 4 + r;
      dst[(size_t)qq * 1024 + nt * 16 + l16] = f2bf(o[nt][r] / lrow[r]);
    }
}

extern "C" void kernel_launch(void* const* d_in, const int* in_sizes, int n_in,
                              void* d_out, int out_size, void* d_ws, size_t ws_size,
                              hipStream_t stream) {
  const float* x = (const float*)d_in[0];
  const float* W_qkv = (const float*)d_in[1];
  const float* b_qkv = (const float*)d_in[2];
  const float* W_out = (const float*)d_in[3];
  const float* b_out = (const float*)d_in[4];
  float* out = (float*)d_out;

  // Layout (ws 32 MiB = 16M shorts; d_out 16 MiB = 8M shorts):
  //   ws:    Qw  [0, 4M)     Kw  [4M, 8M)
  //          Wqt [8M, 11M)   Wot [11M, 12M)   AO [12M, 16M)
  //   d_out: Xb  [0, 4M)     Vw  [4M, 8M)   (both dead before final GEMM
  //          overwrites d_out with the fp32 result)
  // Lifetimes: prep writes Xb,Wqt,Wot. gemm0 reads Xb,Wqt; writes Qw,Kw,Vw.
  // attn reads Qw,Kw,Vw; writes AO. gemm1 reads AO,Wot; writes d_out.
  unsigned short* ws = (unsigned short*)d_ws;
  unsigned short* Qw  = ws;                      // [b,h,s,d] bf16
  unsigned short* Kw  = ws + 4194304;            // [b,h,s,d] bf16
  unsigned short* Wqt = ws + 8388608;            // [3072][1024] bf16 = W_qkv^T
  unsigned short* Wot = ws + 11534336;           // [1024][1024] bf16 = W_out^T
  unsigned short* AO  = ws + 12582912;           // [b,s,h*64+d] bf16
  unsigned short* Xb  = (unsigned short*)d_out;  // [4096][1024] bf16
  unsigned short* Vw  = (unsigned short*)d_out + 4194304;  // [b,h,d,s] bf16

  dim3 blk(256);
  dim3 gblk(512);
  prep<<<dim3(6144), blk, 0, stream>>>(x, W_qkv, W_out, Xb, Wqt, Wot);
  gemm_bt<<<dim3(32, 24), gblk, 0, stream>>>(Xb, Wqt, b_qkv, Qw, Kw, Vw, nullptr, 0);
  attn_kernel<<<dim3(1024), blk, 0, stream>>>(Qw, Kw, Vw, AO);
  gemm_bt<<<dim3(32, 8), gblk, 0, stream>>>(AO, Wot, b_out, nullptr, nullptr, nullptr, out, 1);
}

// Round 13
// 163.193 us; speedup vs baseline: 1.1129x; 1.0148x over previous
//
#include <hip/hip_runtime.h>

typedef __bf16 bf16x8 __attribute__((ext_vector_type(8)));
typedef float f32x4 __attribute__((ext_vector_type(4)));
typedef unsigned short u16x8 __attribute__((ext_vector_type(8)));
typedef unsigned short u16x4 __attribute__((ext_vector_type(4)));

#define MFMA16(a, b, c) __builtin_amdgcn_mfma_f32_16x16x32_bf16((a), (b), (c), 0, 0, 0)

#define WAIT_VM4  asm volatile("s_waitcnt vmcnt(4)" ::: "memory")
#define WAIT_VM2  asm volatile("s_waitcnt vmcnt(2)" ::: "memory")
#define WAIT_VM0  asm volatile("s_waitcnt vmcnt(0)" ::: "memory")
#define WAIT_LGKM asm volatile("s_waitcnt lgkmcnt(0)" ::: "memory")
#define BAR       __builtin_amdgcn_s_barrier()

__device__ __forceinline__ unsigned short f2bf(float f) {
  union { float f; unsigned int i; } v; v.f = f;
  unsigned int u = v.i;
  u += 0x7fffu + ((u >> 16) & 1u);   // RNE
  return (unsigned short)(u >> 16);
}

// async global->LDS, 16B per lane. LDS dest = wave-uniform base + lane*16.
__device__ __forceinline__ void gload16(const void* g, void* l) {
  __builtin_amdgcn_global_load_lds(
      (const __attribute__((address_space(1))) unsigned int*)g,
      (__attribute__((address_space(3))) unsigned int*)l, 16, 0, 0);
}

// ---------------------------------------------------------------------------
// prep: ONE kernel = convert_x + transpose(W_qkv) + transpose(W_out).
// (unchanged from round-11 champion)
// ---------------------------------------------------------------------------
__global__ __launch_bounds__(256) void prep(
    const float* __restrict__ X, const float* __restrict__ Wq,
    const float* __restrict__ Wo, unsigned short* __restrict__ Xb,
    unsigned short* __restrict__ Wqt, unsigned short* __restrict__ Wot) {
  __shared__ unsigned short t[32][33];
  int id = blockIdx.x;
  if (id < 2048) {
    size_t i = (size_t)(id * 256 + threadIdx.x) * 8;
    f32x4 f0 = *(const f32x4*)(X + i);
    f32x4 f1 = *(const f32x4*)(X + i + 4);
    u16x8 tt;
#pragma unroll
    for (int j = 0; j < 4; ++j) { tt[j] = f2bf(f0[j]); tt[4 + j] = f2bf(f1[j]); }
    *(u16x8*)(Xb + i) = tt;
    return;
  }
  const float* W; unsigned short* Wt; int N, bx, by;
  if (id < 5120) { int q = id - 2048; W = Wq; Wt = Wqt; N = 3072; bx = q % 96; by = q / 96; }
  else           { int q = id - 5120; W = Wo; Wt = Wot; N = 1024; bx = q % 32; by = q / 32; }
  int tx = threadIdx.x & 31, ty = threadIdx.x >> 5;   // 32 x 8
#pragma unroll
  for (int j = 0; j < 4; ++j) {
    int r = ty + j * 8;
    t[tx][r] = f2bf(W[(size_t)(by * 32 + r) * N + bx * 32 + tx]);
  }
  __syncthreads();
#pragma unroll
  for (int j = 0; j < 4; ++j) {
    int r = ty + j * 8;   // output row (N index)
    Wt[(size_t)(bx * 32 + r) * 1024 + by * 32 + tx] = t[r][tx];
  }
}

// ---------------------------------------------------------------------------
// m97-lineage GEMM, 8-wave + DEPTH-2 counted-vmcnt pipeline (round 13).
// Round-12 compile fix: the char* Ab[3] = {(char*)As0,...} pointer array
// forced an addrspacecast static initializer (rejected on gfx950). Since the
// loop steps t += 3, every %3 buffer index is positionally constant — the
// rotation is unrolled with explicit As0/As1/As2 names. Schedule identical:
//   STAGE(t+2 -> buf2); vmcnt(4)  // 6 in flight, drain exactly tile t
//   BAR; COMPUTE(buf0); lgkmcnt(0); BAR;  ... (rotate)
// Mechanism: A/B stream from HBM (~900cy); depth-1 gave only ~1 compute
// phase (~400cy) of cover; depth-2 gives ~2 phases. Buffer reuse race-free
// (tile t-1's readers passed the prior LGKM+BAR). Accumulation order
// unchanged -> bit-identical output. Tail drains vmcnt 2 -> 0.
// mode 0: N=3072, scatter Q[b,h,s,d], K[b,h,s,d], V[b,h,d,s] bf16.
// mode 1: N=1024, store FP32 to OF[m*1024+n].
// ---------------------------------------------------------------------------
__global__ __launch_bounds__(512) void gemm_bt(
    const unsigned short* __restrict__ A, const unsigned short* __restrict__ Bt,
    const float* __restrict__ bias,
    unsigned short* __restrict__ O0, unsigned short* __restrict__ O1,
    unsigned short* __restrict__ O2, float* __restrict__ OF, int mode) {
  __shared__ __align__(16) unsigned short As0[128 * 32];
  __shared__ __align__(16) unsigned short Bs0[128 * 32];
  __shared__ __align__(16) unsigned short As1[128 * 32];
  __shared__ __align__(16) unsigned short Bs1[128 * 32];
  __shared__ __align__(16) unsigned short As2[128 * 32];
  __shared__ __align__(16) unsigned short Bs2[128 * 32];

  const int K = 1024;
  int tid = threadIdx.x;
  int lane = tid & 63, wave = tid >> 6, quad = lane >> 4, l16 = lane & 15;
  int wr = wave >> 2, wc = wave & 3;
  int m0 = blockIdx.x * 128, n0 = blockIdx.y * 128;

  int srow = tid >> 2, su = tid & 3;
  const unsigned short* ag = A + (size_t)(m0 + srow) * K + su * 8;
  const unsigned short* bg = Bt + (size_t)(n0 + srow) * K + su * 8;
  int loff = tid * 16;

  int abase = (wr * 64 + l16) * 64 + quad * 16;   // + mt*1024, mt 0..3
  int bbase = (wc * 32 + l16) * 64 + quad * 16;   // + nt*1024, nt 0..1

  f32x4 acc[4][2];
#pragma unroll
  for (int i = 0; i < 4; ++i)
#pragma unroll
    for (int j = 0; j < 2; ++j) acc[i][j] = f32x4{0.f, 0.f, 0.f, 0.f};

  auto STAGE = [&](int k0, unsigned short* Asb, unsigned short* Bsb) {
    gload16(ag + k0, (char*)Asb + loff);
    gload16(bg + k0, (char*)Bsb + loff);
  };
  auto COMPUTE = [&](const unsigned short* Asb, const unsigned short* Bsb) {
    bf16x8 af[4], bfr[2];
#pragma unroll
    for (int t = 0; t < 4; ++t)
      af[t] = *(const bf16x8*)((const char*)Asb + abase + t * 1024);
#pragma unroll
    for (int t = 0; t < 2; ++t)
      bfr[t] = *(const bf16x8*)((const char*)Bsb + bbase + t * 1024);
#pragma unroll
    for (int mt = 0; mt < 4; ++mt)
#pragma unroll
      for (int nt = 0; nt < 2; ++nt)
        acc[mt][nt] = MFMA16(af[mt], bfr[nt], acc[mt][nt]);
  };

  STAGE(0, As0, Bs0);                             // prologue: tiles 0,1 in flight
  STAGE(32, As1, Bs1);
  for (int t = 0; t < 30; t += 3) {               // t multiple of 3: %3 indices fixed
    STAGE((t + 2) * 32, As2, Bs2);                // tile t+2 -> buf2
    WAIT_VM4; BAR;                                // tile t landed (buf0)
    COMPUTE(As0, Bs0);
    WAIT_LGKM; BAR;                               // buf0 free for restage
    STAGE((t + 3) * 32, As0, Bs0);                // tile t+3 -> buf0
    WAIT_VM4; BAR;                                // tile t+1 landed (buf1)
    COMPUTE(As1, Bs1);
    WAIT_LGKM; BAR;                               // buf1 free for restage
    STAGE((t + 4) * 32, As1, Bs1);                // tile t+4 -> buf1
    WAIT_VM4; BAR;                                // tile t+2 landed (buf2)
    COMPUTE(As2, Bs2);
    WAIT_LGKM; BAR;                               // buf2 free for restage
  }
  // after loop: tiles 30 (buf0) and 31 (buf1) still in flight
  WAIT_VM2; BAR;                                  // tile 30 landed
  COMPUTE(As0, Bs0);
  WAIT_LGKM; BAR;
  WAIT_VM0; BAR;                                  // tile 31 landed
  COMPUTE(As1, Bs1);

  if (mode == 0) {
#pragma unroll
    for (int nt = 0; nt < 2; ++nt) {
      int n = n0 + wc * 32 + nt * 16 + l16;
      float bv = bias[n];
      int seg = n >> 10, cc = n & 1023, hh = cc >> 6, d = cc & 63;
#pragma unroll
      for (int mt = 0; mt < 4; ++mt) {
        int mb = m0 + wr * 64 + mt * 16 + quad * 4;
        int b = mb >> 11, s = mb & 2047;
        if (seg == 2) {
          u16x4 pk;
#pragma unroll
          for (int r = 0; r < 4; ++r) pk[r] = f2bf(acc[mt][nt][r] + bv);
          *(u16x4*)&O2[((size_t)((b << 4) + hh) * 64 + d) * 2048 + s] = pk;  // V[b,h,d,s]
        } else {
          unsigned short* O = seg ? O1 : O0;
#pragma unroll
          for (int r = 0; r < 4; ++r)
            O[((size_t)((b << 4) + hh) * 2048 + (s + r)) * 64 + d] = f2bf(acc[mt][nt][r] + bv);
        }
      }
    }
  } else {
#pragma unroll
    for (int nt = 0; nt < 2; ++nt) {
      int n = n0 + wc * 32 + nt * 16 + l16;
      float bv = bias[n];
#pragma unroll
      for (int mt = 0; mt < 4; ++mt) {
        int mb = m0 + wr * 64 + mt * 16 + quad * 4;
#pragma unroll
        for (int r = 0; r < 4; ++r)
          OF[(size_t)(mb + r) * 1024 + n] = acc[mt][nt][r] + bv;   // FP32 output
      }
    }
  }
}

// ---------------------------------------------------------------------------
// MFMA windowed flash attention — EXACT round-3/11 champion version
// (LDS-staged K/V, 4 waves, per-row online softmax). Unchanged.
// ---------------------------------------------------------------------------
__global__ __launch_bounds__(256) void attn_kernel(
    const unsigned short* __restrict__ Q, const unsigned short* __restrict__ Kq,
    const unsigned short* __restrict__ Vt, unsigned short* __restrict__ AO) {
  __shared__ __align__(16) unsigned short Ks[32][72];      // [key][d]
  __shared__ __align__(16) unsigned short Vs[64][40];      // [d][key]
  __shared__ __align__(16) unsigned short Ps[4][16][40];   // per-wave P: [q][key]

  int bid = blockIdx.x;
  int qblk = bid & 31, h = (bid >> 5) & 15, b = bid >> 9;
  int q0 = qblk * 64;
  int tid = threadIdx.x, lane = tid & 63, wave = tid >> 6, quad = lane >> 4, l16 = lane & 15;

  const unsigned short* Qb = Q + (size_t)(((b << 4) + h) * 2048) * 64;
  const unsigned short* Kb = Kq + (size_t)(((b << 4) + h) * 2048) * 64;
  const unsigned short* Vb = Vt + (size_t)(((b << 4) + h) * 64) * 2048;

  int qrow = q0 + wave * 16 + l16;   // A-frag row m = lane&15
  bf16x8 qf0 = __builtin_bit_cast(bf16x8, *(const u16x8*)&Qb[(size_t)qrow * 64 + quad * 8]);
  bf16x8 qf1 = __builtin_bit_cast(bf16x8, *(const u16x8*)&Qb[(size_t)qrow * 64 + 32 + quad * 8]);

  float mrow[4], lrow[4];
  f32x4 zero = {0.f, 0.f, 0.f, 0.f};
  f32x4 o[4];
#pragma unroll
  for (int i = 0; i < 4; ++i) o[i] = zero;
#pragma unroll
  for (int r = 0; r < 4; ++r) { mrow[r] = -1e30f; lrow[r] = 0.f; }

  const float SCALE = 0.125f;  // 64^-0.5
  int pstart = (wave >= 2) ? 1 : 0;
  int pend = pstart + 8;

  int ki = tid >> 3, kc = (tid & 7) * 8;   // K stage: 32 keys x 64 d
  int vd = tid >> 2, vc = (tid & 3) * 8;   // V stage: 64 d x 32 keys

  for (int p = 0; p < 10; ++p) {
    int kbase = q0 + p * 32;
    {
      int s = kbase + ki; s = s > 2047 ? 2047 : s;   // clamp; masked later
      *(u16x8*)&Ks[ki][kc] = *(const u16x8*)&Kb[(size_t)s * 64 + kc];
    }
    if (kbase + vc + 7 <= 2047) {
      *(u16x8*)&Vs[vd][vc] = *(const u16x8*)&Vb[(size_t)vd * 2048 + kbase + vc];
    } else {
#pragma unroll
      for (int j = 0; j < 8; ++j) {
        int s = kbase + vc + j; s = s > 2047 ? 2047 : s;
        Vs[vd][vc + j] = Vb[(size_t)vd * 2048 + s];
      }
    }
    __syncthreads();

    if (p >= pstart && p <= pend) {
      // S = Q K^T : B-frag = K[key=lane&15][d=quad*8+j]
      f32x4 sc[2];
#pragma unroll
      for (int t = 0; t < 2; ++t) {
        bf16x8 kf0 = __builtin_bit_cast(bf16x8, *(const u16x8*)&Ks[t * 16 + l16][quad * 8]);
        bf16x8 kf1 = __builtin_bit_cast(bf16x8, *(const u16x8*)&Ks[t * 16 + l16][32 + quad * 8]);
        f32x4 z = zero;
        z = MFMA16(qf0, kf0, z);
        z = MFMA16(qf1, kf1, z);
        sc[t] = z;
      }
      float sv[2][4];
#pragma unroll
      for (int t = 0; t < 2; ++t)
#pragma unroll
        for (int r = 0; r < 4; ++r) {
          int kg = kbase + t * 16 + l16;
          int qg = q0 + wave * 16 + quad * 4 + r;
          bool valid = (kg >= qg) && (kg <= qg + 255) && (kg < 2048);
          sv[t][r] = valid ? sc[t][r] * SCALE : -1e30f;
        }
#pragma unroll
      for (int r = 0; r < 4; ++r) {
        float v = fmaxf(sv[0][r], sv[1][r]);
        v = fmaxf(v, __shfl_xor(v, 1));
        v = fmaxf(v, __shfl_xor(v, 2));
        v = fmaxf(v, __shfl_xor(v, 4));
        v = fmaxf(v, __shfl_xor(v, 8));
        float mnew = fmaxf(mrow[r], v);
        float alpha = __expf(mrow[r] - mnew);
        mrow[r] = mnew;
        float p0 = __expf(sv[0][r] - mnew);
        float p1 = __expf(sv[1][r] - mnew);
        p0 = (sv[0][r] > -5e29f) ? p0 : 0.f;
        p1 = (sv[1][r] > -5e29f) ? p1 : 0.f;
        float rs = p0 + p1;
        rs += __shfl_xor(rs, 1);
        rs += __shfl_xor(rs, 2);
        rs += __shfl_xor(rs, 4);
        rs += __shfl_xor(rs, 8);
        lrow[r] = lrow[r] * alpha + rs;
#pragma unroll
        for (int nt = 0; nt < 4; ++nt) o[nt][r] *= alpha;
        Ps[wave][quad * 4 + r][l16] = f2bf(p0);
        Ps[wave][quad * 4 + r][16 + l16] = f2bf(p1);
      }
      __threadfence_block();
      bf16x8 pf = __builtin_bit_cast(bf16x8, *(const u16x8*)&Ps[wave][l16][quad * 8]);
#pragma unroll
      for (int nt = 0; nt < 4; ++nt) {
        bf16x8 vf = __builtin_bit_cast(bf16x8, *(const u16x8*)&Vs[nt * 16 + l16][quad * 8]);
        o[nt] = MFMA16(pf, vf, o[nt]);
      }
    }
    __syncthreads();
  }

  unsigned short* dst = AO + ((size_t)(b * 2048 + q0 + wave * 16) * 1024) + h * 64;
#pragma unroll
  for (int nt = 0; nt < 4; ++nt)
#pragma unroll
    for (int r = 0; r < 4; ++r) {
      int qq = quad * 4 + r;
      dst[(size_t)qq * 1024 + nt * 16 + l16] = f2bf(o[nt][r] / lrow[r]);
    }
}

extern "C" void kernel_launch(void* const* d_in, const int* in_sizes, int n_in,
                              void* d_out, int out_size, void* d_ws, size_t ws_size,
                              hipStream_t stream) {
  const float* x = (const float*)d_in[0];
  const float* W_qkv = (const float*)d_in[1];
  const float* b_qkv = (const float*)d_in[2];
  const float* W_out = (const float*)d_in[3];
  const float* b_out = (const float*)d_in[4];
  float* out = (float*)d_out;

  // Layout (ws 32 MiB = 16M shorts; d_out 16 MiB = 8M shorts):
  //   ws:    Qw  [0, 4M)     Kw  [4M, 8M)
  //          Wqt [8M, 11M)   Wot [11M, 12M)   AO [12M, 16M)
  //   d_out: Xb  [0, 4M)     Vw  [4M, 8M)   (both dead before final GEMM
  //          overwrites d_out with the fp32 result)
  unsigned short* ws = (unsigned short*)d_ws;
  unsigned short* Qw  = ws;                      // [b,h,s,d] bf16
  unsigned short* Kw  = ws + 4194304;            // [b,h,s,d] bf16
  unsigned short* Wqt = ws + 8388608;            // [3072][1024] bf16 = W_qkv^T
  unsigned short* Wot = ws + 11534336;           // [1024][1024] bf16 = W_out^T
  unsigned short* AO  = ws + 12582912;           // [b,s,h*64+d] bf16
  unsigned short* Xb  = (unsigned short*)d_out;  // [4096][1024] bf16
  unsigned short* Vw  = (unsigned short*)d_out + 4194304;  // [b,h,d,s] bf16

  dim3 blk(256);
  dim3 gblk(512);
  prep<<<dim3(6144), blk, 0, stream>>>(x, W_qkv, W_out, Xb, Wqt, Wot);
  gemm_bt<<<dim3(32, 24), gblk, 0, stream>>>(Xb, Wqt, b_qkv, Qw, Kw, Vw, nullptr, 0);
  attn_kernel<<<dim3(1024), blk, 0, stream>>>(Qw, Kw, Vw, AO);
  gemm_bt<<<dim3(32, 8), gblk, 0, stream>>>(AO, Wot, b_out, nullptr, nullptr, nullptr, out, 1);
}